// Round 1
// baseline (726.814 us; speedup 1.0000x reference)
//
#include <hip/hip_runtime.h>
#include <hip/hip_bf16.h>
#include <cstdint>
#include <cstddef>

// Problem constants
#define B_TOK 8192
#define HID   4096
#define NH    32
#define NKV   8
#define DH    128
#define RB    128
#define KDIM  4096
#define NOUT  5120   // q (32*128) + k (8*128) columns; v columns are never used
#define QKVW  6144

typedef __bf16 bf16x8 __attribute__((ext_vector_type(8)));
typedef __bf16 bf16x4 __attribute__((ext_vector_type(4)));
typedef float  f32x4  __attribute__((ext_vector_type(4)));

// ---- async global->LDS, 16B per lane. LDS dest = wave-uniform base + lane*16 ----
__device__ __forceinline__ void async_ld16(const void* g, void* l) {
  __builtin_amdgcn_global_load_lds(
      (__attribute__((address_space(1))) void*)(g),
      (__attribute__((address_space(3))) void*)(l), 16, 0, 0);
}

// (tanh(x)+1)/2 == sigmoid(2x) = 1/(1+exp2(-2*log2e*x))
__device__ __forceinline__ float code_of(float x) {
  const float e = exp2f(x * -2.885390081777927f);
  return __builtin_amdgcn_rcpf(1.0f + e);
}

// ---------------- conversion kernels ----------------

__global__ void conv_hidden_kernel(const float* __restrict__ x,
                                   __bf16* __restrict__ y, int n4) {
  const int i = blockIdx.x * 256 + threadIdx.x;
  if (i >= n4) return;
  const float4 v = ((const float4*)x)[i];
  bf16x4 o;
  o[0] = (__bf16)v.x; o[1] = (__bf16)v.y; o[2] = (__bf16)v.z; o[3] = (__bf16)v.w;
  ((bf16x4*)y)[i] = o;
}

// proj_w [4096][6144] -> Wt [5120][4096] bf16 (transpose of first 5120 cols)
__global__ void conv_wt_kernel(const float* __restrict__ W, __bf16* __restrict__ Wt) {
  __shared__ float t[32][33];
  const int n0 = blockIdx.x * 32;   // over NOUT
  const int k0 = blockIdx.y * 32;   // over KDIM
  const int tx = threadIdx.x;       // 0..31
  const int ty = threadIdx.y;       // 0..7
#pragma unroll
  for (int j = 0; j < 4; ++j)
    t[ty + j * 8][tx] = W[(size_t)(k0 + ty + j * 8) * QKVW + n0 + tx];
  __syncthreads();
#pragma unroll
  for (int j = 0; j < 4; ++j)
    Wt[(size_t)(n0 + ty + j * 8) * KDIM + k0 + tx] = (__bf16)t[tx][ty + j * 8];
}

// hash_w [128][128] -> hwT [rbit][d] bf16
__global__ void conv_hash_kernel(const float* __restrict__ hw, __bf16* __restrict__ hwT) {
  const int r = blockIdx.x;    // rbit
  const int d = threadIdx.x;   // dim
  hwT[r * RB + d] = (__bf16)hw[(size_t)d * RB + r];
}

// ---------------- main GEMM: C[8192][5120] = A[8192][4096] @ Bt[5120][4096]^T + bias ----------------

__global__ void gemm_qk(const __bf16* __restrict__ A,
                        const __bf16* __restrict__ Bt,
                        const float* __restrict__ bias,
                        __bf16* __restrict__ C) {
  __shared__ __bf16 As[128 * 32];
  __shared__ __bf16 Bs[128 * 32];

  const int tid  = threadIdx.x;
  const int lane = tid & 63;
  const int wave = tid >> 6;
  const int m0 = blockIdx.y * 128;
  const int n0 = blockIdx.x * 128;
  const int waveM = (wave >> 1) * 64;
  const int waveN = (wave & 1) * 64;

  // staging decomposition: each global_load_lds covers 16 rows x 32 bf16
  const int srow  = lane >> 2;        // row within 16-row chunk
  const int selem = (lane & 3) * 8;   // element offset within 32-elem row

  const __bf16* ga0 = A + (size_t)(m0 + wave * 16 + srow) * KDIM + selem;
  const __bf16* ga1 = ga0 + (size_t)64 * KDIM;
  const __bf16* gb0 = Bt + (size_t)(n0 + wave * 16 + srow) * KDIM + selem;
  const __bf16* gb1 = gb0 + (size_t)64 * KDIM;
  __bf16* la0 = As + wave * 512;         // wave-uniform LDS base
  __bf16* la1 = As + (wave + 4) * 512;
  __bf16* lb0 = Bs + wave * 512;
  __bf16* lb1 = Bs + (wave + 4) * 512;

  const int fr = lane & 15;           // fragment row (m or n)
  const int fk = (lane >> 4) * 8;     // fragment k offset

  f32x4 acc[4][4] = {};

  for (int kt = 0; kt < KDIM / 32; ++kt) {
    const int k0 = kt * 32;
    async_ld16(ga0 + k0, la0);
    async_ld16(ga1 + k0, la1);
    async_ld16(gb0 + k0, lb0);
    async_ld16(gb1 + k0, lb1);
    __syncthreads();

    bf16x8 af[4], bfr[4];
#pragma unroll
    for (int mi = 0; mi < 4; ++mi)
      af[mi] = *(const bf16x8*)(As + (waveM + mi * 16 + fr) * 32 + fk);
#pragma unroll
    for (int ni = 0; ni < 4; ++ni)
      bfr[ni] = *(const bf16x8*)(Bs + (waveN + ni * 16 + fr) * 32 + fk);
#pragma unroll
    for (int mi = 0; mi < 4; ++mi)
#pragma unroll
      for (int ni = 0; ni < 4; ++ni)
        acc[mi][ni] = __builtin_amdgcn_mfma_f32_16x16x32_bf16(af[mi], bfr[ni],
                                                              acc[mi][ni], 0, 0, 0);
    __syncthreads();
  }

  // epilogue: D layout col=lane&15, row=(lane>>4)*4+reg
  const int cl = lane & 15;
  const int rq = (lane >> 4) * 4;
#pragma unroll
  for (int ni = 0; ni < 4; ++ni) {
    const int gn = n0 + waveN + ni * 16 + cl;
    const float bb = bias[gn];
#pragma unroll
    for (int mi = 0; mi < 4; ++mi) {
      const int gm = m0 + waveM + mi * 16 + rq;
#pragma unroll
      for (int r = 0; r < 4; ++r)
        C[(size_t)(gm + r) * NOUT + gn] = (__bf16)(acc[mi][ni][r] + bb);
    }
  }
}

// ---------------- phase 2: per-token dots/norms/hash codes ----------------
// One block per token. Rows 0..31 = q heads, 32..39 = k heads, 40..47 zero pad.

__global__ void phase2_kernel(const __bf16* __restrict__ QK,
                              const __bf16* __restrict__ hwT,
                              float* __restrict__ out) {
  __shared__ __bf16 As[48][136];    // +8 bf16 pad -> conflict-free ds_read_b128
  __shared__ float code[40][129];   // (tanh+1)/2 codes, +1 pad
  __shared__ float rednorm[40];
  __shared__ float reddot[32];

  const int tid  = threadIdx.x;
  const int lane = tid & 63;
  const int wave = tid >> 6;
  const int b = blockIdx.x;

  // stage q,k rows (5120 bf16, contiguous) into padded LDS
  const __bf16* src = QK + (size_t)b * NOUT;
  for (int i = tid; i < 640; i += 256) {
    const int row = i >> 4;
    const int col = (i & 15) * 8;
    *(uint4*)(&As[row][col]) = *(const uint4*)(src + i * 8);
  }
  {
    __bf16* pad = &As[40][0];
    for (int i = tid; i < 8 * 136; i += 256) pad[i] = (__bf16)0.0f;
  }

  // B fragments (hash_w^T) straight from global — identical 32 KB for every
  // block, L2/L1-hot. Wave w owns n-tiles {w, w+4}.
  const int fr = lane & 15;
  const int fk = (lane >> 4) * 8;
  bf16x8 bf[2][4];
#pragma unroll
  for (int nn = 0; nn < 2; ++nn) {
    const int ni = wave + nn * 4;
#pragma unroll
    for (int ks = 0; ks < 4; ++ks)
      bf[nn][ks] = *(const bf16x8*)(hwT + (size_t)(ni * 16 + fr) * RB + ks * 32 + fk);
  }
  __syncthreads();

  // hash codes via MFMA: code[row][rbit] = sigmoid(2 * (In @ hwT^T))
#pragma unroll
  for (int mi = 0; mi < 3; ++mi) {
    bf16x8 af[4];
#pragma unroll
    for (int ks = 0; ks < 4; ++ks)
      af[ks] = *(const bf16x8*)(&As[mi * 16 + fr][ks * 32 + fk]);
#pragma unroll
    for (int nn = 0; nn < 2; ++nn) {
      const int ni = wave + nn * 4;
      f32x4 acc = {0.f, 0.f, 0.f, 0.f};
#pragma unroll
      for (int ks = 0; ks < 4; ++ks)
        acc = __builtin_amdgcn_mfma_f32_16x16x32_bf16(af[ks], bf[nn][ks], acc, 0, 0, 0);
      const int row0 = mi * 16 + (lane >> 4) * 4;
      const int col  = ni * 16 + (lane & 15);
#pragma unroll
      for (int r = 0; r < 4; ++r) {
        const int row = row0 + r;
        if (row < 40) code[row][col] = code_of(acc[r]);
      }
    }
  }

  // norms (tasks 0..39) and q·k dots (tasks 40..71), one wave per task
  for (int task = wave; task < 72; task += 4) {
    float s;
    if (task < 40) {
      const float x0 = (float)As[task][lane * 2];
      const float x1 = (float)As[task][lane * 2 + 1];
      s = x0 * x0 + x1 * x1;
    } else {
      const int h  = task - 40;
      const int kr = 32 + (h >> 2);
      const float q0 = (float)As[h][lane * 2],  q1 = (float)As[h][lane * 2 + 1];
      const float k0 = (float)As[kr][lane * 2], k1 = (float)As[kr][lane * 2 + 1];
      s = q0 * k0 + q1 * k1;
    }
#pragma unroll
    for (int off = 32; off > 0; off >>= 1) s += __shfl_down(s, off);
    if (lane == 0) {
      if (task < 40) rednorm[task] = s; else reddot[task - 40] = s;
    }
  }
  __syncthreads();

  // final: thread (h, sub) sums 16 rbits of |qc - kc|, 8-thread shuffle reduce
  const int h   = tid >> 3;
  const int sub = tid & 7;
  const int kr  = 32 + (h >> 2);
  float s = 0.f;
#pragma unroll
  for (int j = 0; j < 16; ++j) {
    const int r = sub * 16 + j;
    s += fabsf(code[h][r] - code[kr][r]);
  }
  s += __shfl_down(s, 4, 8);
  s += __shfl_down(s, 2, 8);
  s += __shfl_down(s, 1, 8);
  if (sub == 0) {
    const float invsq = 0.08838834764831843f;  // 1/sqrt(128)
    out[(size_t)b * NH + h] = reddot[h] * invsq;
    const float hamw = (1.0f - s * (1.0f / 64.0f)) *
                       sqrtf(rednorm[h]) * sqrtf(rednorm[kr]) * invsq;
    out[(size_t)(B_TOK * NH) + (size_t)b * NH + h] = hamw;
  }
}

// ---------------- launch ----------------

extern "C" void kernel_launch(void* const* d_in, const int* in_sizes, int n_in,
                              void* d_out, int out_size, void* d_ws, size_t ws_size,
                              hipStream_t stream) {
  const float* hidden = (const float*)d_in[0];   // [8192][4096]
  const float* proj_w = (const float*)d_in[1];   // [4096][6144]
  const float* proj_b = (const float*)d_in[2];   // [6144]
  const float* hash_w = (const float*)d_in[3];   // [128][128]
  float* out = (float*)d_out;                    // [2*262144]

  char* w = (char*)d_ws;
  __bf16* Abf = (__bf16*)(w);                                     // 67,108,864 B
  __bf16* Wt  = (__bf16*)(w + 67108864);                          // 41,943,040 B
  __bf16* QK  = (__bf16*)(w + 67108864 + 41943040);               // 83,886,080 B
  __bf16* hwT = (__bf16*)(w + 67108864 + 41943040 + 83886080);    // 32,768 B

  conv_hidden_kernel<<<32768, 256, 0, stream>>>(hidden, Abf, (B_TOK * HID) / 4);
  conv_wt_kernel<<<dim3(NOUT / 32, KDIM / 32), dim3(32, 8), 0, stream>>>(proj_w, Wt);
  conv_hash_kernel<<<RB, DH, 0, stream>>>(hash_w, hwT);
  gemm_qk<<<dim3(NOUT / 128, B_TOK / 128), 256, 0, stream>>>(Abf, Wt, proj_b, QK);
  phase2_kernel<<<B_TOK, 256, 0, stream>>>(QK, hwT, out);
}